// Round 8
// baseline (101.759 us; speedup 1.0000x reference)
//
#include <hip/hip_runtime.h>

#define SEQ   3456
#define DH    32
#define FPT   216
#define NT    16
#define IMG0  20
#define SCALE 0.17677669529663687f

#define KPAD   40    // Ks row stride (u16): 80 B
#define VPAD   168   // Vt small row stride (u16): 336 B (dword 84 ≡ 20 mod 32)
#define IPAD   232   // Vt img row stride (u16): 464 B (dword 116 ≡ 20 mod 32)
#define PPITCH 40    // P row stride (u16): 80 B

typedef __attribute__((ext_vector_type(8))) short bf16x8;
typedef __attribute__((ext_vector_type(4))) float f32x4;

#define MFMA16(a,b,c) __builtin_amdgcn_mfma_f32_16x16x32_bf16(a,b,c,0,0,0)

__device__ __forceinline__ unsigned short bfh(float f) {      // fp32->bf16 RTNE
    unsigned u = __float_as_uint(f);
    u += 0x7FFFu + ((u >> 16) & 1u);
    return (unsigned short)(u >> 16);
}
__device__ __forceinline__ float bff(unsigned short h) {
    return __uint_as_float((unsigned)h << 16);
}
__device__ __forceinline__ void split8(const float* f, bf16x8& hi, bf16x8& lo) {
    #pragma unroll
    for (int j = 0; j < 8; ++j) {
        unsigned short h = bfh(f[j]);
        hi[j] = (short)h;
        lo[j] = (short)bfh(f[j] - bff(h));
    }
}

// 32-bit key-visibility windows over the 160 small keys (g = d*20+jj),
// verified rounds 6-7. Truncated at nkeys at runtime.
__constant__ unsigned MN_TAB[5] = {0xFEFFFFFFu, 0xFFFFEFFFu, 0xFFEFFFFEu,
                                   0xEFFFFEFFu, 0xFFFEFFFFu};
__constant__ unsigned MJ_TAB[5] = {0x00FFFFFFu, 0xF0000F00u, 0x000F0000u,
                                   0x0F0000F0u, 0x0000F000u};

// Layouts (m89/m118/m120-verified):
//  A-frag 16x16x32: A[m = lane&15][k = (lane>>4)*8 + j]
//  B-frag:          B[k = (lane>>4)*8 + j][n = lane&15]
//  C/D:             D[row = (lane>>4)*4 + reg][col = lane&15]
// Wave plan per (bh,t): grid.z splits into 2 WGs.
//  half0: w0/w1 = img tiles 0/1 (7 units each, V^T from LDS);
//         w2/w3 = small tiles {0,2}/{1,3}; tile0/1 partials -> LDS merge.
//  half1: w0:{4,5,6} w1:{7,8,9} w2:{10,11} w3:{12,13}  (direct store)
__global__ __launch_bounds__(256)
void eye_attn_mfma5(const float* __restrict__ q, const float* __restrict__ k,
                    const float* __restrict__ v, float* __restrict__ out) {
    __shared__ __align__(16) unsigned short KsHi[160 * KPAD];    // 12.8 KB
    __shared__ __align__(16) unsigned short VtHi[DH * VPAD];     // 10.5 KB
    __shared__ __align__(16) unsigned short VtImg[DH * IPAD];    // 14.9 KB
    __shared__ __align__(16) unsigned short Pu[4 * 16 * PPITCH]; // 5.1 KB
    __shared__ float Mg[2][64][13];                              // 6.7 KB

    const int t = blockIdx.x, bh = blockIdx.y, half = blockIdx.z;
    const int tid = threadIdx.x;
    const size_t base = (size_t)bh * SEQ * DH;
    const int dmax = (t < 7) ? t : 7;
    const int nkeys = IMG0 * (dmax + 1);
    const int nkt = (nkeys + 31) >> 5;

    // ---- stage: small K rows + small V^T (1280 items), img V^T (1792) ----
    for (int i = tid; i < 3072; i += 256) {   // branch uniform per 256-step
        if (i < 1280) {
            const int g = i >> 3, c = i & 7;
            float4 kk = make_float4(0.f,0.f,0.f,0.f);
            float4 vv = make_float4(0.f,0.f,0.f,0.f);
            if (g < nkeys) {
                const int d = g / IMG0, jj = g - d * IMG0;
                const size_t row = base + (size_t)((t - d) * FPT + jj) * DH + c * 4;
                kk = *(const float4*)(k + row);
                vv = *(const float4*)(v + row);
            }
            const float kf[4] = {kk.x, kk.y, kk.z, kk.w};
            const float vf[4] = {vv.x, vv.y, vv.z, vv.w};
            ushort4 khi;
            unsigned short* ah = (unsigned short*)&khi;
            #pragma unroll
            for (int e = 0; e < 4; ++e) ah[e] = bfh(kf[e]);
            *(ushort4*)(KsHi + g * KPAD + c * 4) = khi;
            #pragma unroll
            for (int e = 0; e < 4; ++e)
                VtHi[(c * 4 + e) * VPAD + g] = bfh(vf[e]);
        } else {
            const int ii = i - 1280;
            const int gi = ii >> 3, c = ii & 7;
            float4 vv = make_float4(0.f,0.f,0.f,0.f);
            if (gi < 196) {
                const size_t row = base + (size_t)(t * FPT + IMG0 + gi) * DH + c * 4;
                vv = *(const float4*)(v + row);
            }
            const float vf[4] = {vv.x, vv.y, vv.z, vv.w};
            #pragma unroll
            for (int e = 0; e < 4; ++e)
                VtImg[(c * 4 + e) * IPAD + gi] = bfh(vf[e]);
        }
    }
    __syncthreads();

    const int wv = tid >> 6, lane = tid & 63;
    const int col = lane & 15, quad = lane >> 4;

    // runtime-truncated small-key visibility masks (wave-uniform)
    unsigned mNt[5], mJt[5];
    #pragma unroll
    for (int kt = 0; kt < 5; ++kt) {
        const int tr = nkeys - kt * 32;
        unsigned mn = MN_TAB[kt], mj = MJ_TAB[kt];
        if (tr <= 0) { mn = 0u; mj = 0u; }
        else if (tr < 32) { const unsigned lim = (1u << tr) - 1u; mn &= lim; mj &= lim; }
        mNt[kt] = mn; mJt[kt] = mj;
    }

    bf16x8 bones;   // B[k][0] = 1: row-sum via MFMA -> l lands in col 0
    #pragma unroll
    for (int j = 0; j < 8; ++j) bones[j] = (short)(col == 0 ? 0x3F80 : 0);

    unsigned short* myP = Pu + wv * 16 * PPITCH;

    const bool isImgWave = (half == 0) && (wv < 2);

    // small-tile list
    int tl[3]; int ntile = 0;
    if (half == 0) {
        if (wv >= 2) { tl[0] = wv - 2; tl[1] = wv; ntile = 2; }   // {0,2},{1,3}
    } else {
        if (wv == 0)      { tl[0]=4;  tl[1]=5;  tl[2]=6; ntile = 3; }
        else if (wv == 1) { tl[0]=7;  tl[1]=8;  tl[2]=9; ntile = 3; }
        else if (wv == 2) { tl[0]=10; tl[1]=11; ntile = 2; }
        else              { tl[0]=12; tl[1]=13; ntile = 2; }
    }

    f32x4 ioacc0 = {0.f,0.f,0.f,0.f}, ioacc1 = {0.f,0.f,0.f,0.f};
    f32x4 ilacc  = {0.f,0.f,0.f,0.f};

    if (isImgWave) {
        // ---- img path: tile wv, 7 units of 32 same-t img keys ----
        const int mb = wv * 16;
        bf16x8 qhi, qlo;
        {
            const int qc = min(mb + col, FPT - 1);
            const float* qp = q + base + (size_t)(t * FPT + qc) * DH + quad * 8;
            float qf[8];
            const float4 a0 = *(const float4*)qp;
            const float4 a1 = *(const float4*)(qp + 4);
            qf[0]=a0.x*SCALE; qf[1]=a0.y*SCALE; qf[2]=a0.z*SCALE; qf[3]=a0.w*SCALE;
            qf[4]=a1.x*SCALE; qf[5]=a1.y*SCALE; qf[6]=a1.z*SCALE; qf[7]=a1.w*SCALE;
            split8(qf, qhi, qlo);
        }
        for (int kt2 = 0; kt2 < 7; ++kt2) {
            f32x4 s[2];
            #pragma unroll
            for (int h = 0; h < 2; ++h) {
                const int keyc = min(IMG0 + kt2 * 32 + h * 16 + col, FPT - 1);
                const float* kp = k + base + (size_t)(t * FPT + keyc) * DH + quad * 8;
                float kf[8];
                const float4 a0 = *(const float4*)kp;
                const float4 a1 = *(const float4*)(kp + 4);
                kf[0]=a0.x; kf[1]=a0.y; kf[2]=a0.z; kf[3]=a0.w;
                kf[4]=a1.x; kf[5]=a1.y; kf[6]=a1.z; kf[7]=a1.w;
                bf16x8 khi;
                #pragma unroll
                for (int j = 0; j < 8; ++j) khi[j] = (short)bfh(kf[j]);
                f32x4 acc = {0.f,0.f,0.f,0.f};
                acc = MFMA16(qhi, khi, acc);
                acc = MFMA16(qlo, khi, acc);
                s[h] = acc;
            }
            #pragma unroll
            for (int h = 0; h < 2; ++h) {
                const int key = IMG0 + kt2 * 32 + h * 16 + col;
                #pragma unroll
                for (int r = 0; r < 4; ++r) {
                    const int qm = mb + quad * 4 + r;
                    const bool vis = (key < FPT) && (qm < IMG0);
                    const float e = vis ? __expf(s[h][r]) : 0.f;
                    myP[(quad * 4 + r) * PPITCH + h * 16 + col] = bfh(e);
                }
            }
            const bf16x8 phi = *(const bf16x8*)(myP + col * PPITCH + quad * 8);
            #pragma unroll
            for (int h = 0; h < 2; ++h) {
                const int dim = h * 16 + col;
                const bf16x8 vhi = *(const bf16x8*)(VtImg + dim * IPAD + kt2 * 32 + quad * 8);
                f32x4& oa = h ? ioacc1 : ioacc0;
                oa = MFMA16(phi, vhi, oa);
            }
            ilacc = MFMA16(phi, bones, ilacc);
        }
    } else {
        // ---- small-key path over tile list ----
        for (int mi = 0; mi < ntile; ++mi) {
            const int mb = tl[mi] * 16;
            bf16x8 qhi, qlo;
            {
                const int qc = min(mb + col, FPT - 1);
                const float* qp = q + base + (size_t)(t * FPT + qc) * DH + quad * 8;
                float qf[8];
                const float4 a0 = *(const float4*)qp;
                const float4 a1 = *(const float4*)(qp + 4);
                qf[0]=a0.x*SCALE; qf[1]=a0.y*SCALE; qf[2]=a0.z*SCALE; qf[3]=a0.w*SCALE;
                qf[4]=a1.x*SCALE; qf[5]=a1.y*SCALE; qf[6]=a1.z*SCALE; qf[7]=a1.w*SCALE;
                split8(qf, qhi, qlo);
            }
            f32x4 oacc0 = {0.f,0.f,0.f,0.f}, oacc1 = {0.f,0.f,0.f,0.f};
            f32x4 lacc = {0.f,0.f,0.f,0.f};
            for (int kt = 0; kt < nkt; ++kt) {
                f32x4 s[2];
                #pragma unroll
                for (int h = 0; h < 2; ++h) {
                    const int key = kt * 32 + h * 16 + col;
                    const bf16x8 khi = *(const bf16x8*)(KsHi + key * KPAD + quad * 8);
                    f32x4 acc = {0.f,0.f,0.f,0.f};
                    acc = MFMA16(qhi, khi, acc);
                    acc = MFMA16(qlo, khi, acc);
                    s[h] = acc;
                }
                #pragma unroll
                for (int r = 0; r < 4; ++r) {
                    const int qm = mb + quad * 4 + r;
                    const bool isj = (qm >= 4) && (qm < IMG0);
                    const unsigned m = (qm < FPT) ? (isj ? mJt[kt] : mNt[kt]) : 0u;
                    #pragma unroll
                    for (int h = 0; h < 2; ++h) {
                        const float e = ((m >> (h * 16 + col)) & 1u)
                                        ? __expf(s[h][r]) : 0.f;
                        myP[(quad * 4 + r) * PPITCH + h * 16 + col] = bfh(e);
                    }
                }
                const bf16x8 phi = *(const bf16x8*)(myP + col * PPITCH + quad * 8);
                #pragma unroll
                for (int h = 0; h < 2; ++h) {
                    const int dim = h * 16 + col;
                    const bf16x8 vhi = *(const bf16x8*)(VtHi + dim * VPAD + kt * 32 + quad * 8);
                    f32x4& oa = h ? oacc1 : oacc0;
                    oa = MFMA16(phi, vhi, oa);
                }
                lacc = MFMA16(phi, bones, lacc);
            }
            if (half == 0 && mi == 0) {
                // tile0/1 small partial -> merge buffer (img wave finishes it)
                float* mp = &Mg[wv - 2][lane][0];
                #pragma unroll
                for (int r = 0; r < 4; ++r) {
                    mp[r]     = lacc[r];
                    mp[4 + r] = oacc0[r];
                    mp[8 + r] = oacc1[r];
                }
            } else {
                #pragma unroll
                for (int r = 0; r < 4; ++r) {
                    const float lr = __shfl(lacc[r], lane & 48);
                    const float inv = 1.f / lr;
                    const int qm = mb + quad * 4 + r;
                    if (qm < FPT) {
                        float* op = out + base + (size_t)(t * FPT + qm) * DH;
                        op[col]      = oacc0[r] * inv;
                        op[16 + col] = oacc1[r] * inv;
                    }
                }
            }
        }
    }

    if (half == 0) {
        __syncthreads();
        if (wv < 2) {
            // merge small partial (from w2/w3) + img acc, normalize, store
            const float* mp = &Mg[wv][lane][0];
            #pragma unroll
            for (int r = 0; r < 4; ++r) {
                ilacc[r]  += mp[r];
                ioacc0[r] += mp[4 + r];
                ioacc1[r] += mp[8 + r];
            }
            const int mb = wv * 16;
            #pragma unroll
            for (int r = 0; r < 4; ++r) {
                const float lr = __shfl(ilacc[r], lane & 48);
                const float inv = 1.f / lr;
                const int qm = mb + quad * 4 + r;
                if (qm < FPT) {
                    float* op = out + base + (size_t)(t * FPT + qm) * DH;
                    op[col]      = ioacc0[r] * inv;
                    op[16 + col] = ioacc1[r] * inv;
                }
            }
        }
    }
}

extern "C" void kernel_launch(void* const* d_in, const int* in_sizes, int n_in,
                              void* d_out, int out_size, void* d_ws, size_t ws_size,
                              hipStream_t stream) {
    const float* q = (const float*)d_in[0];
    const float* k = (const float*)d_in[1];
    const float* v = (const float*)d_in[2];
    float* out = (float*)d_out;
    const int BH = in_sizes[0] / (SEQ * DH);   // 24
    dim3 grid(NT, BH, 2);                      // 768 WGs = 3/CU even
    eye_attn_mfma5<<<grid, 256, 0, stream>>>(q, k, v, out);
}

// Round 9
// 99.144 us; speedup vs baseline: 1.0264x; 1.0264x over previous
//
#include <hip/hip_runtime.h>

#define SEQ   3456
#define DH    32
#define FPT   216
#define NT    16
#define IMG0  20
// SCALE * log2(e): QK^T lands in log2 domain; exp2f == v_exp_f32 (1 instr)
#define SCALE2 0.2550707067f

#define KPAD   40    // Ks row stride (u16): 80 B (2-way bank alias: free)
#define VPAD   168   // Vt small row stride (u16): 336 B
#define IPAD   232   // Vt img row stride (u16): 464 B
#define PPITCH 40    // P row stride (u16): 80 B

typedef __attribute__((ext_vector_type(8))) short bf16x8;
typedef __attribute__((ext_vector_type(4))) float f32x4;

#define MFMA16(a,b,c) __builtin_amdgcn_mfma_f32_16x16x32_bf16(a,b,c,0,0,0)

__device__ __forceinline__ unsigned short bfh(float f) {      // fp32->bf16 RTNE
    unsigned u = __float_as_uint(f);
    u += 0x7FFFu + ((u >> 16) & 1u);
    return (unsigned short)(u >> 16);
}
__device__ __forceinline__ float bff(unsigned short h) {
    return __uint_as_float((unsigned)h << 16);
}
__device__ __forceinline__ void split8(const float* f, bf16x8& hi, bf16x8& lo) {
    #pragma unroll
    for (int j = 0; j < 8; ++j) {
        unsigned short h = bfh(f[j]);
        hi[j] = (short)h;
        lo[j] = (short)bfh(f[j] - bff(h));
    }
}

// 32-bit key-visibility windows over the 160 small keys (g = d*20+jj),
// verified rounds 7-8. Truncated at nkeys at runtime.
__constant__ unsigned MN_TAB[5] = {0xFEFFFFFFu, 0xFFFFEFFFu, 0xFFEFFFFEu,
                                   0xEFFFFEFFu, 0xFFFEFFFFu};
__constant__ unsigned MJ_TAB[5] = {0x00FFFFFFu, 0xF0000F00u, 0x000F0000u,
                                   0x0F0000F0u, 0x0000F000u};

// Layouts (m89/m118/m120-verified):
//  A-frag 16x16x32: A[m = lane&15][k = (lane>>4)*8 + j]
//  B-frag:          B[k = (lane>>4)*8 + j][n = lane&15]
//  C/D:             D[row = (lane>>4)*4 + reg][col = lane&15]
// Numerics: QK = qhi*khi + qlo*khi (2-term; k_lo noise ~1e-3 of sigma).
// PV/l hi-only: P rounding cancels in the softmax ratio.
// Design rule (rounds 7/8): at 3 WG/CU co-residency, total work sets the
// time — never add chip-wide work to buy wave balance.
__global__ __launch_bounds__(256)
void eye_attn_mfma6(const float* __restrict__ q, const float* __restrict__ k,
                    const float* __restrict__ v, float* __restrict__ out) {
    __shared__ __align__(16) unsigned short KsHi[160 * KPAD];    // 12.8 KB
    __shared__ __align__(16) unsigned short VtHi[DH * VPAD];     // 10.5 KB
    __shared__ __align__(16) unsigned short VtImg[DH * IPAD];    // 14.9 KB
    __shared__ __align__(16) unsigned short Pu[4 * 16 * PPITCH]; // 5.1 KB

    const int t = blockIdx.x, bh = blockIdx.y, half = blockIdx.z;
    const int tid = threadIdx.x;
    const size_t base = (size_t)bh * SEQ * DH;
    const int dmax = (t < 7) ? t : 7;
    const int nkeys = IMG0 * (dmax + 1);
    const int nkt = (nkeys + 31) >> 5;

    // ---- stage small K rows + small V^T: only the nkeys live rows ----
    for (int i = tid; i < nkeys * 8; i += 256) {
        const int g = i >> 3, c = i & 7;
        const int d = g / IMG0, jj = g - d * IMG0;
        const size_t row = base + (size_t)((t - d) * FPT + jj) * DH + c * 4;
        const float4 kk = *(const float4*)(k + row);
        const float4 vv = *(const float4*)(v + row);
        const float kf[4] = {kk.x, kk.y, kk.z, kk.w};
        const float vf[4] = {vv.x, vv.y, vv.z, vv.w};
        ushort4 khi;
        unsigned short* ah = (unsigned short*)&khi;
        #pragma unroll
        for (int e = 0; e < 4; ++e) ah[e] = bfh(kf[e]);
        *(ushort4*)(KsHi + g * KPAD + c * 4) = khi;
        #pragma unroll
        for (int e = 0; e < 4; ++e)
            VtHi[(c * 4 + e) * VPAD + g] = bfh(vf[e]);
    }
    // zero V^T tail cols [nkeys, nkt*32) — P is 0 there but garbage V could
    // be NaN (0 * NaN = NaN would poison PV). K garbage is exp-masked: safe.
    {
        const int rem = nkeys - (nkt - 1) * 32;   // live cols in last unit
        if (rem < 32) {
            for (int i = tid; i < 1024; i += 256) {
                const int c = i & 31;
                if (c >= rem)
                    VtHi[(i >> 5) * VPAD + (nkt - 1) * 32 + c] = 0;
            }
        }
    }
    // ---- img V^T (224 cols, zero-padded past 196): half-0 WGs only ----
    if (half == 0) {
        for (int i = tid; i < 1792; i += 256) {
            const int gi = i >> 3, c = i & 7;
            float4 vv = make_float4(0.f, 0.f, 0.f, 0.f);
            if (gi < 196) {
                const size_t row = base + (size_t)(t * FPT + IMG0 + gi) * DH + c * 4;
                vv = *(const float4*)(v + row);
            }
            const float vf[4] = {vv.x, vv.y, vv.z, vv.w};
            #pragma unroll
            for (int e = 0; e < 4; ++e)
                VtImg[(c * 4 + e) * IPAD + gi] = bfh(vf[e]);
        }
    }
    __syncthreads();   // only barrier; Pu regions are wave-private below

    const int wv = tid >> 6, lane = tid & 63;
    const int col = lane & 15, quad = lane >> 4;

    // runtime-truncated small-key visibility masks (wave-uniform)
    unsigned mNt[5], mJt[5];
    #pragma unroll
    for (int kt = 0; kt < 5; ++kt) {
        const int tr = nkeys - kt * 32;
        unsigned mn = MN_TAB[kt], mj = MJ_TAB[kt];
        if (tr <= 0) { mn = 0u; mj = 0u; }
        else if (tr < 32) { const unsigned lim = (1u << tr) - 1u; mn &= lim; mj &= lim; }
        mNt[kt] = mn; mJt[kt] = mj;
    }

    bf16x8 bones;   // B[k][0] = 1: row-sum via MFMA -> l lands in col 0
    #pragma unroll
    for (int j = 0; j < 8; ++j) bones[j] = (short)(col == 0 ? 0x3F80 : 0);

    unsigned short* myP = Pu + wv * 16 * PPITCH;

    // tile plan (round-6 best): half0 w0:{0}+img w1:{1}+img w2:{2,3} w3:{4,5}
    //                           half1 w0:{6,7} w1:{8,9} w2:{10,11} w3:{12,13}
    int mt[2]; int mcnt; bool do_img = false;
    if (half == 0) {
        if (wv == 0)      { mt[0] = 0; mcnt = 1; do_img = true; }
        else if (wv == 1) { mt[0] = 1; mcnt = 1; do_img = true; }
        else if (wv == 2) { mt[0] = 2; mt[1] = 3; mcnt = 2; }
        else              { mt[0] = 4; mt[1] = 5; mcnt = 2; }
    } else {
        mt[0] = 6 + 2 * wv; mt[1] = 7 + 2 * wv; mcnt = 2;
    }

    for (int mi = 0; mi < mcnt; ++mi) {
        const int mb = mt[mi] * 16;
        bf16x8 qhi, qlo;
        {
            const int qc = min(mb + col, FPT - 1);   // clamp; store is masked
            const float* qp = q + base + (size_t)(t * FPT + qc) * DH + quad * 8;
            float qf[8];
            const float4 a0 = *(const float4*)qp;
            const float4 a1 = *(const float4*)(qp + 4);
            qf[0]=a0.x*SCALE2; qf[1]=a0.y*SCALE2; qf[2]=a0.z*SCALE2; qf[3]=a0.w*SCALE2;
            qf[4]=a1.x*SCALE2; qf[5]=a1.y*SCALE2; qf[6]=a1.z*SCALE2; qf[7]=a1.w*SCALE2;
            split8(qf, qhi, qlo);
        }
        f32x4 oacc0 = {0.f,0.f,0.f,0.f}, oacc1 = {0.f,0.f,0.f,0.f};
        f32x4 lacc = {0.f,0.f,0.f,0.f};

        // ---- small keys: QK^T -> mask/exp2 -> P(bf16) roundtrip -> PV+l ----
        for (int kt = 0; kt < nkt; ++kt) {
            f32x4 s[2];
            #pragma unroll
            for (int h = 0; h < 2; ++h) {
                const int key = kt * 32 + h * 16 + col;
                const bf16x8 khi = *(const bf16x8*)(KsHi + key * KPAD + quad * 8);
                f32x4 acc = {0.f,0.f,0.f,0.f};
                acc = MFMA16(qhi, khi, acc);
                acc = MFMA16(qlo, khi, acc);
                s[h] = acc;
            }
            #pragma unroll
            for (int r = 0; r < 4; ++r) {
                const int qm = mb + quad * 4 + r;
                const bool isj = (qm >= 4) && (qm < IMG0);
                const unsigned m = (qm < FPT) ? (isj ? mJt[kt] : mNt[kt]) : 0u;
                #pragma unroll
                for (int h = 0; h < 2; ++h) {
                    const float e = ((m >> (h * 16 + col)) & 1u)
                                    ? exp2f(s[h][r]) : 0.f;
                    myP[(quad * 4 + r) * PPITCH + h * 16 + col] = bfh(e);
                }
            }
            const bf16x8 phi = *(const bf16x8*)(myP + col * PPITCH + quad * 8);
            #pragma unroll
            for (int h = 0; h < 2; ++h) {
                const int dim = h * 16 + col;
                const bf16x8 vhi = *(const bf16x8*)(VtHi + dim * VPAD + kt * 32 + quad * 8);
                f32x4& oa = h ? oacc1 : oacc0;
                oa = MFMA16(phi, vhi, oa);
            }
            lacc = MFMA16(phi, bones, lacc);
        }

        // ---- same-t img keys (20..215): queries qm<20 (tiles 0,1) ----
        if (mi == 0 && do_img) {
            for (int kt2 = 0; kt2 < 7; ++kt2) {
                f32x4 s[2];
                #pragma unroll
                for (int h = 0; h < 2; ++h) {
                    const int keyc = min(IMG0 + kt2 * 32 + h * 16 + col, FPT - 1);
                    const float* kp = k + base + (size_t)(t * FPT + keyc) * DH + quad * 8;
                    float kf[8];
                    const float4 a0 = *(const float4*)kp;
                    const float4 a1 = *(const float4*)(kp + 4);
                    kf[0]=a0.x; kf[1]=a0.y; kf[2]=a0.z; kf[3]=a0.w;
                    kf[4]=a1.x; kf[5]=a1.y; kf[6]=a1.z; kf[7]=a1.w;
                    bf16x8 khi;
                    #pragma unroll
                    for (int j = 0; j < 8; ++j) khi[j] = (short)bfh(kf[j]);
                    f32x4 acc = {0.f,0.f,0.f,0.f};
                    acc = MFMA16(qhi, khi, acc);
                    acc = MFMA16(qlo, khi, acc);
                    s[h] = acc;
                }
                #pragma unroll
                for (int h = 0; h < 2; ++h) {
                    const int key = IMG0 + kt2 * 32 + h * 16 + col;
                    #pragma unroll
                    for (int r = 0; r < 4; ++r) {
                        const int qm = mb + quad * 4 + r;
                        const bool vis = (key < FPT) && (qm < IMG0);
                        const float e = vis ? exp2f(s[h][r]) : 0.f;
                        myP[(quad * 4 + r) * PPITCH + h * 16 + col] = bfh(e);
                    }
                }
                const bf16x8 phi = *(const bf16x8*)(myP + col * PPITCH + quad * 8);
                #pragma unroll
                for (int h = 0; h < 2; ++h) {
                    const int dim = h * 16 + col;
                    const bf16x8 vhi = *(const bf16x8*)(VtImg + dim * IPAD + kt2 * 32 + quad * 8);
                    f32x4& oa = h ? oacc1 : oacc0;
                    oa = MFMA16(phi, vhi, oa);
                }
                lacc = MFMA16(phi, bones, lacc);
            }
        }

        // ---- epilogue: broadcast l (col 0 of quad), normalize, store ----
        #pragma unroll
        for (int r = 0; r < 4; ++r) {
            const float lr = __shfl(lacc[r], lane & 48);   // lane quad*16 + 0
            const float inv = 1.f / lr;
            const int qm = mb + quad * 4 + r;
            if (qm < FPT) {
                float* op = out + base + (size_t)(t * FPT + qm) * DH;
                op[col]      = oacc0[r] * inv;
                op[16 + col] = oacc1[r] * inv;
            }
        }
    }
}

extern "C" void kernel_launch(void* const* d_in, const int* in_sizes, int n_in,
                              void* d_out, int out_size, void* d_ws, size_t ws_size,
                              hipStream_t stream) {
    const float* q = (const float*)d_in[0];
    const float* k = (const float*)d_in[1];
    const float* v = (const float*)d_in[2];
    float* out = (float*)d_out;
    const int BH = in_sizes[0] / (SEQ * DH);   // 24
    dim3 grid(NT, BH, 2);                      // 768 WGs = 3/CU even
    eye_attn_mfma6<<<grid, 256, 0, stream>>>(q, k, v, out);
}